// Round 12
// baseline (56.422 us; speedup 1.0000x reference)
//
#include <hip/hip_runtime.h>
#include <hip/hip_bf16.h>

// ShuffleNet fused block-MLP, MI355X (gfx950).  R12 = R11 (register-local
// shuffle via k-permuted w2 pack) + forced software pipeline:
//  - named A/B register double-buffer for all per-step loads, with
//    __builtin_amdgcn_sched_barrier(0) fences so hipcc cannot sink loads
//    (fixes the VGPR=52 MLP starvation seen R4-R11),
//  - nontemporal x loads / y stores (keep 1MB weight set L2-resident),
//  - blockIdx decode rt=b&511, npq=b>>9 so the 4 x-sharing WGs land on the
//    same XCD (512 % 8 == 0).
// Math identical to R11 (passed, absmax 9.77e-4).

typedef __attribute__((ext_vector_type(8))) short  short8;   // 8 bf16 = 4 VGPR
typedef __attribute__((ext_vector_type(4))) short  short4v;
typedef __attribute__((ext_vector_type(4))) float  floatx4;

#define XP 1032   // xs row pitch in shorts (516 dw = 4 mod 32 -> bank rotation)

__device__ __forceinline__ short f2bf(float f) {
  union { __hip_bfloat16 h; short s; } u;
  u.h = __float2bfloat16(f);
  return u.s;
}
__device__ __forceinline__ float bf2f(short s) {
  union { float f; unsigned u; } uu;
  uu.u = ((unsigned)(unsigned short)s) << 16;
  return uu.f;
}
__device__ __forceinline__ int pk16(float a, float b) {
  return (int)(unsigned short)f2bf(a) | ((int)(unsigned short)f2bf(b) << 16);
}

// gelu(v) ~= v * sigmoid(1.5957691*(v + 0.044715 v^3)), exp2-folded (abs<5e-4)
__device__ __forceinline__ float gelu_f(float v) {
  float m = v * v;
  float c = fmaf(-0.1029375f, m, -2.3020807f);
  float z = v * c;
  float e = __builtin_amdgcn_exp2f(z);
  return v * __builtin_amdgcn_rcpf(1.0f + e);
}

// ---- pack kernel: w1 frags | w2 frags (pi-permuted) | b1 frags (bf16) ----
__global__ void pack_k(const float* __restrict__ w1, const float* __restrict__ w2,
                       const float* __restrict__ b1, short* __restrict__ w1p,
                       short* __restrict__ w2p, short* __restrict__ b1p) {
  const int t = blockIdx.x * blockDim.x + threadIdx.x;  // 160*512 = 81920
  const int lane = t & 63;
  const int lhi = lane >> 4;
  if (t < 32768) {  // w1 frag (n,np,ks): lane l elem e = w1[n][np*16+(l&15)][ks*32+lhi*8+e]
    const int ks = (t >> 6) & 1, np = (t >> 7) & 15, n = (t >> 11) & 15;
    const float* src = w1 + ((size_t)(n * 256 + np * 16 + (lane & 15)) * 64 + ks * 32 + lhi * 8);
    short8 f;
#pragma unroll
    for (int e = 0; e < 8; ++e) f[e] = f2bf(src[e]);
    *(short8*)(w1p + (size_t)t * 8) = f;
  } else if (t < 65536) {  // w2 frag (np,s,ot), pi-permuted k
    const int t2 = t - 32768;
    const int ot = (t2 >> 6) & 3, s = (t2 >> 8) & 7, np = (t2 >> 11) & 15;
    const int op = ot * 16 + (lane & 15);
    short8 f;
#pragma unroll
    for (int e = 0; e < 8; ++e) {
      // physical k = s*32 + lhi*8 + e ; chunk index Kc = pi(k):
      const int Kc = 32 * s + 16 * ((e >> 2) & 1) + 4 * lhi + (e & 3);
      const int n = Kc >> 4, ohi = Kc & 15;
      f[e] = f2bf(w2[(size_t)(np * 64 + op) * 256 + ohi * 16 + n]);
    }
    *(short8*)(w2p + (size_t)t2 * 8) = f;
  } else {  // b1 frag (n,np): lane l reg r = bf16(b1[(np*16+lhi*4+r)*16+n])
    const int t3 = t - 65536;  // 16384
    const int np = (t3 >> 6) & 15, n = (t3 >> 10) & 15;
    short4v b;
#pragma unroll
    for (int r = 0; r < 4; ++r) b[r] = f2bf(b1[(np * 16 + lhi * 4 + r) * 16 + n]);
    *(short4v*)(b1p + (size_t)((n * 16 + np) * 64 + lane) * 4) = b;
  }
}

// ---- per-step load set (named registers; macro = rule #20-safe) ----
#define DECLF(F) \
  short8 F##wf00, F##wf01, F##wf10, F##wf11, F##bf0, F##bf1, F##bf2, F##bf3, \
         F##xa0, F##xa1, F##xb0, F##xb1; \
  short4v F##bv0, F##bv1;

#define LOADS(F, s) { \
  const int n0_ = 2 * (s), n1_ = 2 * (s) + 1; \
  F##wf00 = *(const short8*)(w1p + (size_t)(((n0_ * 16 + np) * 2 + 0) * 64 + lane) * 8); \
  F##wf01 = *(const short8*)(w1p + (size_t)(((n0_ * 16 + np) * 2 + 1) * 64 + lane) * 8); \
  F##wf10 = *(const short8*)(w1p + (size_t)(((n1_ * 16 + np) * 2 + 0) * 64 + lane) * 8); \
  F##wf11 = *(const short8*)(w1p + (size_t)(((n1_ * 16 + np) * 2 + 1) * 64 + lane) * 8); \
  F##bv0  = *(const short4v*)(b1p + (size_t)((n0_ * 16 + np) * 64 + lane) * 4); \
  F##bv1  = *(const short4v*)(b1p + (size_t)((n1_ * 16 + np) * 64 + lane) * 4); \
  F##bf0  = *(const short8*)(w2p + (size_t)(((np * 8 + (s)) * 4 + 0) * 64 + lane) * 8); \
  F##bf1  = *(const short8*)(w2p + (size_t)(((np * 8 + (s)) * 4 + 1) * 64 + lane) * 8); \
  F##bf2  = *(const short8*)(w2p + (size_t)(((np * 8 + (s)) * 4 + 2) * 64 + lane) * 8); \
  F##bf3  = *(const short8*)(w2p + (size_t)(((np * 8 + (s)) * 4 + 3) * 64 + lane) * 8); \
  F##xa0  = *(const short8*)(&xs[l15 * XP + n0_ * 64 + lhi * 8]); \
  F##xa1  = *(const short8*)(&xs[l15 * XP + n0_ * 64 + 32 + lhi * 8]); \
  F##xb0  = *(const short8*)(&xs[l15 * XP + n1_ * 64 + lhi * 8]); \
  F##xb1  = *(const short8*)(&xs[l15 * XP + n1_ * 64 + 32 + lhi * 8]); \
}

#define STEPC(F) { \
  floatx4 a0_ = {0.f,0.f,0.f,0.f}, a1_ = {0.f,0.f,0.f,0.f}; \
  a0_ = __builtin_amdgcn_mfma_f32_16x16x32_bf16(F##wf00, F##xa0, a0_, 0, 0, 0); \
  a0_ = __builtin_amdgcn_mfma_f32_16x16x32_bf16(F##wf01, F##xa1, a0_, 0, 0, 0); \
  a1_ = __builtin_amdgcn_mfma_f32_16x16x32_bf16(F##wf10, F##xb0, a1_, 0, 0, 0); \
  a1_ = __builtin_amdgcn_mfma_f32_16x16x32_bf16(F##wf11, F##xb1, a1_, 0, 0, 0); \
  union { int i[4]; short8 v; } af_; \
  af_.i[0] = pk16(gelu_f(a0_[0] + bf2f(F##bv0[0])), gelu_f(a0_[1] + bf2f(F##bv0[1]))); \
  af_.i[1] = pk16(gelu_f(a0_[2] + bf2f(F##bv0[2])), gelu_f(a0_[3] + bf2f(F##bv0[3]))); \
  af_.i[2] = pk16(gelu_f(a1_[0] + bf2f(F##bv1[0])), gelu_f(a1_[1] + bf2f(F##bv1[1]))); \
  af_.i[3] = pk16(gelu_f(a1_[2] + bf2f(F##bv1[2])), gelu_f(a1_[3] + bf2f(F##bv1[3]))); \
  c0 = __builtin_amdgcn_mfma_f32_16x16x32_bf16(af_.v, F##bf0, c0, 0, 0, 0); \
  c1 = __builtin_amdgcn_mfma_f32_16x16x32_bf16(af_.v, F##bf1, c1, 0, 0, 0); \
  c2 = __builtin_amdgcn_mfma_f32_16x16x32_bf16(af_.v, F##bf2, c2, 0, 0, 0); \
  c3 = __builtin_amdgcn_mfma_f32_16x16x32_bf16(af_.v, F##bf3, c3, 0, 0, 0); \
}

#define SB __builtin_amdgcn_sched_barrier(0);

// ---- fused: 2048 WGs x 256 thr; WG = (rt = b&511, npq = b>>9) ----
__global__ __launch_bounds__(256, 3) void fused_k(
    const float* __restrict__ x, const short* __restrict__ w1p,
    const short* __restrict__ w2p, const short* __restrict__ b1p,
    const float* __restrict__ b2, float* __restrict__ y) {
  __shared__ __align__(16) short xs[16 * XP];   // 33 KB staged x

  const int tid = threadIdx.x;
  const int wv = tid >> 6, lane = tid & 63;
  const int l15 = lane & 15, lhi = lane >> 4;
  const int rt  = blockIdx.x & 511;        // x-sharing WGs are 512 apart ->
  const int np  = (blockIdx.x >> 9) * 4 + wv;  // same XCD (512 % 8 == 0)

  // ---- stage: 16 rows x 1024 f32 -> bf16 LDS (nontemporal, 1KB/inst) ----
#pragma unroll
  for (int p = 0; p < 4; ++p) {
    const int row = wv * 4 + p;
#pragma unroll
    for (int q = 0; q < 4; ++q) {
      const int col = q * 256 + lane * 4;
      floatx4 v = __builtin_nontemporal_load(
          (const floatx4*)(x + (size_t)(rt * 16 + row) * 1024 + col));
      short4v sv;
#pragma unroll
      for (int e = 0; e < 4; ++e) sv[e] = f2bf(v[e]);
      *(short4v*)(&xs[row * XP + col]) = sv;
    }
  }
  __syncthreads();   // the only barrier

  floatx4 c0 = {0.f,0.f,0.f,0.f}, c1 = {0.f,0.f,0.f,0.f};
  floatx4 c2 = {0.f,0.f,0.f,0.f}, c3 = {0.f,0.f,0.f,0.f};

  DECLF(A) DECLF(B)

  LOADS(A, 0)
  LOADS(B, 1) SB STEPC(A)
  LOADS(A, 2) SB STEPC(B)
  LOADS(B, 3) SB STEPC(A)
  LOADS(A, 4) SB STEPC(B)
  LOADS(B, 5) SB STEPC(A)
  LOADS(A, 6) SB STEPC(B)
  LOADS(B, 7) SB STEPC(A)
  SB STEPC(B)

  // ---- y store (nontemporal): col = np*64+ot*16+l15, rows rt*16+lhi*4+r ----
  floatx4 cc[4] = {c0, c1, c2, c3};
#pragma unroll
  for (int ot = 0; ot < 4; ++ot) {
    const int col = np * 64 + ot * 16 + l15;
    const float bb = b2[col];
    float* py = y + (size_t)(rt * 16 + lhi * 4) * 1024 + col;
#pragma unroll
    for (int r = 0; r < 4; ++r)
      __builtin_nontemporal_store(cc[ot][r] + bb, py + (size_t)r * 1024);
  }
}

extern "C" void kernel_launch(void* const* d_in, const int* in_sizes, int n_in,
                              void* d_out, int out_size, void* d_ws, size_t ws_size,
                              hipStream_t stream) {
  const float* x  = (const float*)d_in[0];
  const float* w1 = (const float*)d_in[1];
  const float* b1 = (const float*)d_in[2];
  const float* w2 = (const float*)d_in[3];
  const float* b2 = (const float*)d_in[4];
  float* y = (float*)d_out;

  short* w1p = (short*)d_ws;               // 512 KB
  short* w2p = w1p + 16 * 256 * 64;        // 512 KB
  short* b1p = w2p + 16 * 256 * 64;        // 128 KB

  pack_k<<<160, 512, 0, stream>>>(w1, w2, b1, w1p, w2p, b1p);
  fused_k<<<2048, 256, 0, stream>>>(x, w1p, w2p, b1p, b2, y);
}